// Round 6
// baseline (221.808 us; speedup 1.0000x reference)
//
#include <hip/hip_runtime.h>
#include <hip/hip_bf16.h>

// Problem: B=8, S=1024, EMBED=1024, DK=DV=512, M=64. Inputs/outputs f32.
// Identity: landmark selection is a segment permutation P of k, so
// kernel_1 = K3 P^T, pinv(kernel_2) = P pinv(K3), and
// out = K3 K3+ K3 v = K3 v == softmax(q k^T) v  (standard attention).
#define SS   1024
#define DKK  512

typedef __hip_bfloat16 bf16;
typedef __attribute__((ext_vector_type(8))) short s16x8;            // 8 x bf16
typedef __attribute__((ext_vector_type(8))) unsigned short u16x8;
typedef __attribute__((ext_vector_type(4))) float f32x4;

// ---- ws layout (byte offsets), 76 MiB, lifetime-packed ----
// [0,48)   X-bf16 (16 MiB per z)   : alive convert -> proj
// [0,16)   logits (16 MiB)         : alive scores -> pv (reuses dead X-bf16)
// [48,51)  W(z) bf16               : alive convert -> proj
// [51,52)  stats                   : alive scores -> pv
// [52,60) q  [60,68) k  [68,76) vT : alive proj -> end
#define WS_XB(z) (((size_t)(z)) << 24)
#define WS_W(z)  ((48ull << 20) + ((size_t)(z) << 20))
#define WS_ST    (51ull << 20)
#define WS_Q     (52ull << 20)
#define WS_K     (60ull << 20)
#define WS_VT    (68ull << 20)
#define WS_LG    (0ull)

__device__ __forceinline__ void async_ld16(const void* g, void* s) {
  __builtin_amdgcn_global_load_lds(
      (const __attribute__((address_space(1))) void*)g,
      (__attribute__((address_space(3))) void*)s, 16, 0, 0);
}

__device__ __forceinline__ unsigned short f2bfu(float f) {
  return __builtin_bit_cast(unsigned short, __float2bfloat16(f));
}
__device__ __forceinline__ float bfu2f(unsigned short u) {
  unsigned int i = ((unsigned int)u) << 16;
  return __builtin_bit_cast(float, i);
}

// Convert X (3 x 8M elems) and W (3 x 512K elems) f32 -> bf16 into ws.
// 16 elems/thread. X: 3*2048 blocks; W: 3*128 blocks. Grid 6528.
__global__ __launch_bounds__(256)
void convert_all(const float* __restrict__ x0, const float* __restrict__ x1,
                 const float* __restrict__ x2, const float* __restrict__ w0,
                 const float* __restrict__ w1, const float* __restrict__ w2,
                 char* __restrict__ ws)
{
  const int bx = blockIdx.x;
  const float* src;
  unsigned short* dst;
  int local;
  if (bx < 6144) {
    const int z = bx >> 11; local = bx & 2047;
    src = (z == 0) ? x0 : (z == 1) ? x1 : x2;
    dst = (unsigned short*)(ws + WS_XB(z));
  } else {
    const int b2 = bx - 6144;
    const int z = b2 >> 7; local = b2 & 127;
    src = (z == 0) ? w0 : (z == 1) ? w1 : w2;
    dst = (unsigned short*)(ws + WS_W(z));
  }
  const int i = local * 4096 + threadIdx.x * 16;
  const float4* s = (const float4*)(src + i);
  float4 a = s[0], b = s[1], c = s[2], d = s[3];
  u16x8 o0, o1;
  o0[0] = f2bfu(a.x); o0[1] = f2bfu(a.y); o0[2] = f2bfu(a.z); o0[3] = f2bfu(a.w);
  o0[4] = f2bfu(b.x); o0[5] = f2bfu(b.y); o0[6] = f2bfu(b.z); o0[7] = f2bfu(b.w);
  o1[0] = f2bfu(c.x); o1[1] = f2bfu(c.y); o1[2] = f2bfu(c.z); o1[3] = f2bfu(c.w);
  o1[4] = f2bfu(d.x); o1[5] = f2bfu(d.y); o1[6] = f2bfu(d.z); o1[7] = f2bfu(d.w);
  *(u16x8*)(dst + i)     = o0;
  *(u16x8*)(dst + i + 8) = o1;
}

// ---------- bf16 x bf16 core ----------
// C[BM x 128] = A[BM x K] * B[128 x K]^T, both K-contiguous bf16.
// LDS via global_load_lds w=16; LDS[row][slot] holds chunk (slot ^ (row&7)).
// 4 waves, wave tile (BM/2) x 64, acc[mi*4+ni] with MI = BM/32.
template<int BM, int K, int LDA, int LDB>
__device__ __forceinline__ void gemm_core(const bf16* __restrict__ A,
                                          const bf16* __restrict__ Bw,
                                          int bm, int bn,
                                          short* As, short* Bs, f32x4* acc)
{
  constexpr int MI = BM / 32;
  constexpr int AR = BM / 4;
  const int tid  = threadIdx.x;
  const int lane = tid & 63;
  const int wave = tid >> 6;
  const int l8   = lane >> 3;
  const int kch  = ((lane & 7) ^ l8) * 8;
  const bf16* ag = A  + (size_t)(bm * BM + wave * AR + l8) * LDA + kch;
  const bf16* bg = Bw + (size_t)(bn * 128 + wave * 32 + l8) * LDB + kch;
  short* AsW = As + wave * AR * 64;
  short* BsW = Bs + wave * 32 * 64;
  const int waveM = wave >> 1, waveN = wave & 1;
  const int l16  = lane & 15;
  const int quad = lane >> 4;
  const int xr   = l16 & 7;

  #pragma unroll
  for (int t = 0; t < MI * 4; ++t)
    #pragma unroll
    for (int r = 0; r < 4; ++r) acc[t][r] = 0.0f;

  for (int kt = 0; kt < K / 64; ++kt) {
    #pragma unroll
    for (int j = 0; j < AR / 8; ++j) async_ld16(ag + (size_t)j * 8 * LDA, AsW + j * 8 * 64);
    #pragma unroll
    for (int j = 0; j < 4; ++j)      async_ld16(bg + (size_t)j * 8 * LDB, BsW + j * 8 * 64);
    ag += 64; bg += 64;
    __syncthreads();
    #pragma unroll
    for (int ks = 0; ks < 2; ++ks) {
      s16x8 af[MI], bfv[4];
      #pragma unroll
      for (int mi = 0; mi < MI; ++mi) {
        const int row  = waveM * (BM / 2) + mi * 16 + l16;
        const int slot = (ks * 4 + quad) ^ xr;
        af[mi] = *(const s16x8*)&As[row * 64 + slot * 8];
      }
      #pragma unroll
      for (int ni = 0; ni < 4; ++ni) {
        const int row  = waveN * 64 + ni * 16 + l16;
        const int slot = (ks * 4 + quad) ^ xr;
        bfv[ni] = *(const s16x8*)&Bs[row * 64 + slot * 8];
      }
      #pragma unroll
      for (int mi = 0; mi < MI; ++mi)
        #pragma unroll
        for (int ni = 0; ni < 4; ++ni)
          acc[mi * 4 + ni] = __builtin_amdgcn_mfma_f32_16x16x32_bf16(
              af[mi], bfv[ni], acc[mi * 4 + ni], 0, 0, 0);
    }
    __syncthreads();
  }
}

// z=0: q = (Xq Wq^T + bq) * 512^-0.5 ; z=1: k = Xk Wk^T + bk ;
// z=2: vT[b][d][s] = (Xv Wv^T + bv)^T.
// Pure bf16 128x128 tiles (m97 structure), K=1024, grid 768 flat.
// The 4 bn-siblings of an A-panel share an XCD (ids differ by 8/16/24).
__global__ __launch_bounds__(256, 3)
void proj_kernel(const bf16* __restrict__ XB, const bf16* __restrict__ W0,
                 const float* __restrict__ bq, const float* __restrict__ bk,
                 const float* __restrict__ bv,
                 bf16* __restrict__ qo, bf16* __restrict__ ko,
                 bf16* __restrict__ vT, float qscale)
{
  __shared__ __align__(16) short As[128 * 64];
  __shared__ __align__(16) short Bs[128 * 64];
  const int id   = blockIdx.x;
  const int xcd  = id & 7;
  const int s    = id >> 3;            // 0..95
  const int bn   = s & 3;              // 0..3
  const int unit = (s >> 2) * 8 + xcd; // 0..191 unique
  const int bm   = unit & 63;
  const int z    = unit >> 6;          // 0..2
  const bf16* A  = XB + ((size_t)z << 23);          // 8M bf16 per z
  const bf16* Bw = W0 + ((size_t)z << 19);
  const float* bias = (z == 0) ? bq : (z == 1) ? bk : bv;
  f32x4 acc[16];
  gemm_core<128, 1024, 1024, 1024>(A, Bw, bm, bn, As, Bs, acc);

  const int lane = threadIdx.x & 63;
  const int wave = threadIdx.x >> 6;
  const int waveM = wave >> 1, waveN = wave & 1;
  const int l16 = lane & 15, quad = lane >> 4;
  const int row0 = bm * 128 + waveM * 64;
  const int col0 = bn * 128 + waveN * 64;
  const float sc = (z == 0) ? qscale : 1.0f;
  bf16* C = (z == 0) ? qo : ko;
  #pragma unroll
  for (int ni = 0; ni < 4; ++ni) {
    const int col = col0 + ni * 16 + l16;
    const float bb = bias[col];
    #pragma unroll
    for (int mi = 0; mi < 4; ++mi)
      #pragma unroll
      for (int r = 0; r < 4; ++r) {
        const int row = row0 + mi * 16 + quad * 4 + r;
        const float v = acc[mi * 4 + ni][r] + bb;
        if (z == 2)
          vT[((size_t)(row >> 10) * DKK + col) * SS + (row & (SS - 1))] =
              __float2bfloat16(v);
        else
          C[(size_t)row * DKK + col] = __float2bfloat16(v * sc);
      }
  }
}

// logits[b][s][t] = q[b][s].k[b][t]; 64x128 tiles + per-chunk softmax stats
// (max, expsum over the bf16-ROUNDED logits, bit-consistent with pv re-read).
// Flat grid 1024 (4 blocks/CU): z = id&7, s = id>>3: bm = s&15, bn = s>>4.
__global__ __launch_bounds__(256, 4)
void scores_kernel(const bf16* __restrict__ q, const bf16* __restrict__ k,
                   bf16* __restrict__ lgB, float* __restrict__ stats)
{
  __shared__ __align__(16) short As[64 * 64];
  __shared__ __align__(16) short Bs[128 * 64];
  const int id = blockIdx.x;
  const int z  = id & 7;
  const int s  = id >> 3;          // 0..127
  const int bm = s & 15;
  const int bn = s >> 4;           // 0..7
  f32x4 acc[8];
  gemm_core<64, 512, 512, 512>(q + (size_t)z * SS * DKK, k + (size_t)z * SS * DKK,
                               bm, bn, As, Bs, acc);

  const int lane = threadIdx.x & 63;
  const int wave = threadIdx.x >> 6;
  const int waveM = wave >> 1, waveN = wave & 1;
  const int l16 = lane & 15, quad = lane >> 4;
  const int row0 = bm * 64 + waveM * 32;
  const int col0 = bn * 128 + waveN * 64;
  bf16* C = lgB + (size_t)z * SS * SS;
  #pragma unroll
  for (int ni = 0; ni < 4; ++ni) {
    const int col = col0 + ni * 16 + l16;
    #pragma unroll
    for (int mi = 0; mi < 2; ++mi)
      #pragma unroll
      for (int r = 0; r < 4; ++r) {
        const int row = row0 + mi * 16 + quad * 4 + r;
        C[(size_t)row * SS + col] = __float2bfloat16(acc[mi * 4 + ni][r]);
      }
  }
  // stats over the 64-col slice this wave owns (16-lane groups share a row)
  const int chunk = bn * 2 + waveN;
  #pragma unroll
  for (int mi = 0; mi < 2; ++mi)
    #pragma unroll
    for (int r = 0; r < 4; ++r) {
      float xr4[4];
      float m = -1e30f;
      #pragma unroll
      for (int ni = 0; ni < 4; ++ni) {
        xr4[ni] = bfu2f(f2bfu(acc[mi * 4 + ni][r]));
        m = fmaxf(m, xr4[ni]);
      }
      #pragma unroll
      for (int msk = 1; msk < 16; msk <<= 1) m = fmaxf(m, __shfl_xor(m, msk));
      float e = 0.f;
      #pragma unroll
      for (int ni = 0; ni < 4; ++ni) e += __expf(xr4[ni] - m);
      #pragma unroll
      for (int msk = 1; msk < 16; msk <<= 1) e += __shfl_xor(e, msk);
      if (l16 == 0) {
        const int row = row0 + mi * 16 + quad * 4 + r;
        float2 mr; mr.x = m; mr.y = e;
        *(float2*)&stats[(((size_t)z * SS + row) * 16 + chunk) * 2] = mr;
      }
    }
}

// ---------- pv core: A = softmax'd logits (exp applied at staging) ----------
__device__ __forceinline__ void gemm_core_pv(const unsigned short* __restrict__ lg,
                                             const bf16* __restrict__ vT,
                                             int bm, int bn,
                                             const float* Ml, const float* Rl,
                                             short* As, short* Bs, f32x4* acc)
{
  const int tid  = threadIdx.x;
  const int lane = tid & 63;
  const int wave = tid >> 6;
  const int l8   = lane >> 3;
  const int kch  = ((lane & 7) ^ l8) * 8;
  const bf16* bg = vT + (size_t)(bn * 128 + wave * 32 + l8) * 1024 + kch;
  short* BsW = Bs + wave * 32 * 64;
  const int arow = tid >> 3;
  const int ag8  = tid & 7;
  const int slotA = (ag8 ^ (arow & 7)) * 8;
  const unsigned short* ag = lg + (size_t)(bm * 64 + arow) * 1024 + ag8 * 8;
  const int waveM = wave >> 1, waveN = wave & 1;
  const int l16  = lane & 15;
  const int quad = lane >> 4;
  const int xr   = l16 & 7;

  #pragma unroll
  for (int t = 0; t < 8; ++t)
    #pragma unroll
    for (int r = 0; r < 4; ++r) acc[t][r] = 0.0f;

  for (int kt = 0; kt < 16; ++kt) {
    #pragma unroll
    for (int j = 0; j < 4; ++j) async_ld16(bg + (size_t)j * 8 * 1024, BsW + j * 8 * 64);
    bg += 64;
    #pragma unroll
    for (int p = 0; p < 2; ++p) {
      const int rl = p * 32 + arow;
      u16x8 u = *(const u16x8*)(ag + (size_t)p * 32 * 1024);
      const float M = Ml[rl], R = Rl[rl];
      u16x8 v;
      #pragma unroll
      for (int j = 0; j < 8; ++j)
        v[j] = f2bfu(__expf(bfu2f((unsigned short)u[j]) - M) * R);
      *(u16x8*)&As[rl * 64 + slotA] = v;
    }
    ag += 64;
    __syncthreads();
    #pragma unroll
    for (int ks = 0; ks < 2; ++ks) {
      s16x8 af[2], bfv[4];
      #pragma unroll
      for (int mi = 0; mi < 2; ++mi) {
        const int row  = waveM * 32 + mi * 16 + l16;
        const int slot = (ks * 4 + quad) ^ xr;
        af[mi] = *(const s16x8*)&As[row * 64 + slot * 8];
      }
      #pragma unroll
      for (int ni = 0; ni < 4; ++ni) {
        const int row  = waveN * 64 + ni * 16 + l16;
        const int slot = (ks * 4 + quad) ^ xr;
        bfv[ni] = *(const s16x8*)&Bs[row * 64 + slot * 8];
      }
      #pragma unroll
      for (int mi = 0; mi < 2; ++mi)
        #pragma unroll
        for (int ni = 0; ni < 4; ++ni)
          acc[mi * 4 + ni] = __builtin_amdgcn_mfma_f32_16x16x32_bf16(
              af[mi], bfv[ni], acc[mi * 4 + ni], 0, 0, 0);
    }
    __syncthreads();
  }
}

// out[b][s][d] = softmax(logits)[b][s][:] . vT[b][d][:]; f32 out.
// Flat grid 512: z = id&7, s = id>>3: bm = s&15, bn = s>>4 (0..3).
__global__ __launch_bounds__(256, 4)
void pv_kernel(const unsigned short* __restrict__ lgB, const bf16* __restrict__ vT,
               const float* __restrict__ stats, float* __restrict__ out)
{
  __shared__ __align__(16) short As[64 * 64];
  __shared__ __align__(16) short Bs[128 * 64];
  __shared__ float Ml[64], Rl[64];
  const int id = blockIdx.x;
  const int z  = id & 7;
  const int s  = id >> 3;          // 0..63
  const int bm = s & 15;
  const int bn = s >> 4;           // 0..3
  const int tid = threadIdx.x;

  if (tid < 64) {
    const int row = bm * 64 + tid;
    const float* st = stats + ((size_t)z * SS + row) * 32;
    float mc[16], lc[16];
    float M = -1e30f;
    #pragma unroll
    for (int c = 0; c < 16; ++c) {
      mc[c] = st[c * 2]; lc[c] = st[c * 2 + 1];
      M = fmaxf(M, mc[c]);
    }
    float L = 0.f;
    #pragma unroll
    for (int c = 0; c < 16; ++c) L += __expf(mc[c] - M) * lc[c];
    Ml[tid] = M; Rl[tid] = 1.0f / L;
  }
  __syncthreads();

  f32x4 acc[8];
  gemm_core_pv(lgB + (size_t)z * SS * SS, vT + (size_t)z * DKK * SS,
               bm, bn, Ml, Rl, As, Bs, acc);

  const int lane = tid & 63;
  const int wave = tid >> 6;
  const int waveM = wave >> 1, waveN = wave & 1;
  const int l16 = lane & 15, quad = lane >> 4;
  const int row0 = bm * 64 + waveM * 32;
  const int col0 = bn * 128 + waveN * 64;
  float* C = out + (size_t)z * SS * DKK;
  #pragma unroll
  for (int ni = 0; ni < 4; ++ni) {
    const int col = col0 + ni * 16 + l16;
    #pragma unroll
    for (int mi = 0; mi < 2; ++mi)
      #pragma unroll
      for (int r = 0; r < 4; ++r) {
        const int row = row0 + mi * 16 + quad * 4 + r;
        C[(size_t)row * DKK + col] = acc[mi * 4 + ni][r];
      }
  }
}

extern "C" void kernel_launch(void* const* d_in, const int* in_sizes, int n_in,
                              void* d_out, int out_size, void* d_ws, size_t ws_size,
                              hipStream_t stream)
{
  char* ws = (char*)d_ws;
  bf16*  XB   = (bf16*)(ws + WS_XB(0));
  bf16*  W0   = (bf16*)(ws + WS_W(0));
  float* stat = (float*)(ws + WS_ST);
  bf16*  q    = (bf16*)(ws + WS_Q);
  bf16*  kk   = (bf16*)(ws + WS_K);
  bf16*  vT   = (bf16*)(ws + WS_VT);
  bf16*  lgB  = (bf16*)(ws + WS_LG);

  const float qscale = 0.044194173824159216f;  // 512^-0.5

  dim3 blk(256, 1, 1);
  // d_in order: qin,kin,vin,Wq,bq,Wk,bk,Wv,bv (all f32)
  hipLaunchKernelGGL(convert_all, dim3(6528), blk, 0, stream,
                     (const float*)d_in[0], (const float*)d_in[1],
                     (const float*)d_in[2], (const float*)d_in[3],
                     (const float*)d_in[5], (const float*)d_in[7], ws);
  hipLaunchKernelGGL(proj_kernel, dim3(768, 1, 1), blk, 0, stream,
                     XB, W0,
                     (const float*)d_in[4], (const float*)d_in[6],
                     (const float*)d_in[8], q, kk, vT, qscale);
  hipLaunchKernelGGL(scores_kernel, dim3(1024, 1, 1), blk, 0, stream,
                     q, kk, lgB, stat);
  hipLaunchKernelGGL(pv_kernel, dim3(512, 1, 1), blk, 0, stream,
                     (const unsigned short*)lgB, vT, stat, (float*)d_out);
}